// Round 3
// baseline (369.637 us; speedup 1.0000x reference)
//
#include <hip/hip_runtime.h>
#include <hip/hip_fp16.h>
#include <cstdint>
#include <cstddef>

// Problem constants
#define DIMK 1024
#define NBATCH 8
#define SEQ 2048

typedef _Float16 half8 __attribute__((ext_vector_type(8)));
typedef _Float16 half4_t __attribute__((ext_vector_type(4)));
typedef float float4_t __attribute__((ext_vector_type(4)));
typedef float floatx16 __attribute__((ext_vector_type(16)));

// async global->LDS 16B copy (gfx950). LDS dest is wave-uniform base + lane*16.
__device__ __forceinline__ void gload16(const _Float16* g, _Float16* l) {
  __builtin_amdgcn_global_load_lds((const __attribute__((address_space(1))) void*)g,
                                   (__attribute__((address_space(3))) void*)l, 16, 0, 0);
}

#define BAR() __builtin_amdgcn_s_barrier()
#define LGKM0() asm volatile("s_waitcnt lgkmcnt(0)" ::: "memory")
#define VMW(n) asm volatile("s_waitcnt vmcnt(" #n ")" ::: "memory")
#define PRIO1() __builtin_amdgcn_s_setprio(1)
#define PRIO0() __builtin_amdgcn_s_setprio(0)
#define SCHED0() __builtin_amdgcn_sched_barrier(0)

// ---------------------------------------------------------------------------
// 256x256-tile NT f16 GEMM core, BK=64, 512 threads = 8 waves (2M x 4N),
// v_mfma_f32_32x32x16_f16 (layout proven in round-0 kernel), 8-phase
// counted-vmcnt pipeline.  LDS 128 KiB: [A|B] x 2 parities; 16B-granule XOR
// swizzle (granule g of row r stored at g^(r&7)); staging pre-swizzles the
// per-lane GLOBAL source so the LDS dest stays linear for global_load_lds.
// Per wave output 128x64 = 4 m-tiles x 2 n-tiles of 32x32; per K-tile:
// 24 ds_read_b128 (A 16, B 8) and 32 MFMA (vs 64 with 16x16 shape).
// A/B frag (32x32x16): m/n = lane&31, k = (lane>>5)*8 + j.
// C/D: col = lane&31, row = (reg&3) + 8*(reg>>2) + 4*(lane>>5).
// ---------------------------------------------------------------------------
__device__ __forceinline__ void gemm256_core(
    const char* __restrict__ Ab, const char* __restrict__ Bb,
    const int ldA, const int ldB, const int NT, _Float16* lds,
    floatx16 (&acc)[4][2])
{
  const int tid = threadIdx.x;
  const int lane = tid & 63, wave = tid >> 6;
  const int warp_m = wave >> 2, warp_n = wave & 3;
  const int srow = lane >> 3;                    // staging sub-row in 8-row chunk
  const int scb = ((lane & 7) ^ srow) << 4;      // pre-swizzled source col-byte
  const int c0 = wave * 2;                       // this wave's 1KB chunk pair
  const int m32 = lane & 31, ksel = lane >> 5, rsw = lane & 7;

  // loop-invariant LDS read offsets (halves); granule for kk = kk*2+ksel
  const int xo0 = ((0 + ksel) ^ rsw) << 3;
  const int xo1 = ((2 + ksel) ^ rsw) << 3;
  const int xo2 = ((4 + ksel) ^ rsw) << 3;
  const int xo3 = ((6 + ksel) ^ rsw) << 3;
  const int aro = (warp_m * 64 + m32) * 64;          // A row base (halves)
  const int bro = 16384 + (warp_n * 32 + m32) * 64;  // B row base (B region)

  // loop-invariant staging bases
  _Float16* const sA = lds + c0 * 512;
  _Float16* const sB = lds + 16384 + c0 * 512;
  const char* const gA = Ab + (size_t)(c0 * 8 + srow) * ldA + scb;
  const char* const gB = Bb + (size_t)(c0 * 8 + srow) * ldB + scb;
  const size_t ldA8 = (size_t)ldA * 8,   ldB8 = (size_t)ldB * 8;
  const size_t ldA128 = (size_t)ldA * 128, ldB128 = (size_t)ldB * 128;

  half8 Af[2][4], Bf0[4], Bf1[4];

#define STG_A(pbuf, ob_, bot) do { \
    _Float16* _lb = sA + (pbuf) + ((bot) ? 8192 : 0); \
    const char* _g = gA + ((bot) ? ldA128 : 0) + (size_t)(ob_); \
    gload16((const _Float16*)_g, _lb); \
    gload16((const _Float16*)(_g + ldA8), _lb + 512); } while (0)
#define STG_B(pbuf, ob_, bot) do { \
    _Float16* _lb = sB + (pbuf) + ((bot) ? 8192 : 0); \
    const char* _g = gB + ((bot) ? ldB128 : 0) + (size_t)(ob_); \
    gload16((const _Float16*)_g, _lb); \
    gload16((const _Float16*)(_g + ldB8), _lb + 512); } while (0)

// A fragments for row-half g (g=0: rows [0,128), g=1: +128): 8 x ds_read_b128
#define LDA_G(g) do { \
    _Pragma("unroll") for (int mt = 0; mt < 2; ++mt) { \
      Af[mt][0] = *(const half8*)(pA0 + (g) * 8192 + mt * 2048); \
      Af[mt][1] = *(const half8*)(pA1 + (g) * 8192 + mt * 2048); \
      Af[mt][2] = *(const half8*)(pA2 + (g) * 8192 + mt * 2048); \
      Af[mt][3] = *(const half8*)(pA3 + (g) * 8192 + mt * 2048); \
    } } while (0)
// B fragments for n-tile nt (B rows nt*128 + warp_n*32): 4 x ds_read_b128
#define LDB_G(g, BF) do { \
      BF[0] = *(const half8*)(pB0 + (g) * 8192); \
      BF[1] = *(const half8*)(pB1 + (g) * 8192); \
      BF[2] = *(const half8*)(pB2 + (g) * 8192); \
      BF[3] = *(const half8*)(pB3 + (g) * 8192); \
    } while (0)

// one C-quadrant x K=64: 8 MFMA (2 m-tiles x 4 kk)
#define QUAD2(mb, nt, BF) do { \
    _Pragma("unroll") for (int mt = 0; mt < 2; ++mt) \
    _Pragma("unroll") for (int kk = 0; kk < 4; ++kk) \
      acc[(mb) + mt][nt] = __builtin_amdgcn_mfma_f32_32x32x16_f16( \
          Af[mt][kk], BF[kk], acc[(mb) + mt][nt], 0, 0, 0); \
  } while (0)

  // prologue: tile0 complete in LDS + 3 half-tiles of tile1 in flight
  STG_A(0, 0, 0); STG_B(0, 0, 0); STG_B(0, 0, 1); STG_A(0, 0, 1);
  STG_A(32768, 128, 0); STG_B(32768, 128, 0); STG_B(32768, 128, 1);
  VMW(6);
  BAR();

  int t = 0;
  for (; t + 2 < NT; ++t) {
    const int pb  = (t & 1) << 15;
    const int pbn = pb ^ 32768;
    const int o1 = (t + 1) << 7, o2 = (t + 2) << 7;
    const _Float16* pA0 = lds + pb + aro + xo0;
    const _Float16* pA1 = lds + pb + aro + xo1;
    const _Float16* pA2 = lds + pb + aro + xo2;
    const _Float16* pA3 = lds + pb + aro + xo3;
    const _Float16* pB0 = lds + pb + bro + xo0;
    const _Float16* pB1 = lds + pb + bro + xo1;
    const _Float16* pB2 = lds + pb + bro + xo2;
    const _Float16* pB3 = lds + pb + bro + xo3;
    // P1: A(lo)+B(lo) reads | stage (t+1, A-bot)
    LDA_G(0); LDB_G(0, Bf0);
    STG_A(pbn, o1, 1);
    BAR(); LGKM0(); SCHED0();
    PRIO1(); QUAD2(0, 0, Bf0); PRIO0();
    BAR();
    // P2: B(hi) reads | stage (t+2, A-top)  [cur-buf A-top dead since P1]
    LDB_G(1, Bf1);
    STG_A(pb, o2, 0);
    BAR(); LGKM0(); SCHED0();
    PRIO1(); QUAD2(0, 1, Bf1); PRIO0();
    BAR();
    // P3: A(hi) reads | stage (t+2, B-top)
    LDA_G(1);
    STG_B(pb, o2, 0);
    BAR(); LGKM0(); SCHED0();
    PRIO1(); QUAD2(2, 1, Bf1); PRIO0();
    BAR();
    // P4: no ds_reads -> no pre-barrier needed | stage (t+2, B-bot) |
    //     counted drain: tile t+1 fully resident after vmcnt(6)
    STG_B(pb, o2, 1);
    PRIO1(); QUAD2(2, 0, Bf0); PRIO0();
    VMW(6);
    BAR();
  }
  // tile NT-2: stage last half-tile (NT-1, A-bot), then full drain
  {
    const int pb  = (t & 1) << 15;
    const int pbn = pb ^ 32768;
    const int oL = (NT - 1) << 7;
    const _Float16* pA0 = lds + pb + aro + xo0;
    const _Float16* pA1 = lds + pb + aro + xo1;
    const _Float16* pA2 = lds + pb + aro + xo2;
    const _Float16* pA3 = lds + pb + aro + xo3;
    const _Float16* pB0 = lds + pb + bro + xo0;
    const _Float16* pB1 = lds + pb + bro + xo1;
    const _Float16* pB2 = lds + pb + bro + xo2;
    const _Float16* pB3 = lds + pb + bro + xo3;
    LDA_G(0); LDB_G(0, Bf0);
    STG_A(pbn, oL, 1);
    BAR(); LGKM0(); SCHED0();
    PRIO1(); QUAD2(0, 0, Bf0); PRIO0();
    BAR();
    LDB_G(1, Bf1);
    BAR(); LGKM0(); SCHED0();
    PRIO1(); QUAD2(0, 1, Bf1); PRIO0();
    BAR();
    LDA_G(1);
    BAR(); LGKM0(); SCHED0();
    PRIO1(); QUAD2(2, 1, Bf1); PRIO0();
    BAR();
    PRIO1(); QUAD2(2, 0, Bf0); PRIO0();
    VMW(0);
    BAR();
  }
  // tile NT-1: everything resident, compiler-managed waits
  {
    const int pb = ((NT - 1) & 1) << 15;
    const _Float16* pA0 = lds + pb + aro + xo0;
    const _Float16* pA1 = lds + pb + aro + xo1;
    const _Float16* pA2 = lds + pb + aro + xo2;
    const _Float16* pA3 = lds + pb + aro + xo3;
    const _Float16* pB0 = lds + pb + bro + xo0;
    const _Float16* pB1 = lds + pb + bro + xo1;
    const _Float16* pB2 = lds + pb + bro + xo2;
    const _Float16* pB3 = lds + pb + bro + xo3;
    LDA_G(0); LDB_G(0, Bf0); LDB_G(1, Bf1);
    QUAD2(0, 0, Bf0); QUAD2(0, 1, Bf1);
    LDA_G(1);
    QUAD2(2, 1, Bf1); QUAD2(2, 0, Bf0);
  }
#undef STG_A
#undef STG_B
#undef LDA_G
#undef LDB_G
#undef QUAD2
}

// C-tile coordinate helpers (32x32 tiles, interleaved wave sub-tiles)
#define ROW32(mt) (warp_m * 64 + ((mt) & 1) * 32 + (((mt) >> 1) ? 128 : 0))
#define COL32(nt) (warp_n * 32 + ((nt) ? 128 : 0))
#define RL32(mt, reg) (ROW32(mt) + ((reg) & 3) + 8 * ((reg) >> 2) + 4 * ksel)

// ---------------------------------------------------------------------------
// One-shot prep: cvt x (4194304 quads), W1 (262144), W2 (262144) to f16.
__global__ __launch_bounds__(256) void prep_kernel(const float* __restrict__ x,
                                                   const float* __restrict__ W1,
                                                   const float* __restrict__ W2,
                                                   _Float16* __restrict__ xh,
                                                   _Float16* __restrict__ Wcat) {
  int i = blockIdx.x * 256 + threadIdx.x;
  if (i < 4194304) {
    float4_t v = ((const float4_t*)x)[i];
    half4_t h; h[0]=(_Float16)v[0]; h[1]=(_Float16)v[1]; h[2]=(_Float16)v[2]; h[3]=(_Float16)v[3];
    ((half4_t*)xh)[i] = h;
  } else if (i < 4456448) {
    int j = i - 4194304;
    float4_t v = ((const float4_t*)W1)[j];
    half4_t h; h[0]=(_Float16)v[0]; h[1]=(_Float16)v[1]; h[2]=(_Float16)v[2]; h[3]=(_Float16)v[3];
    ((half4_t*)Wcat)[j] = h;
  } else if (i < 4718592) {
    int j = i - 4456448;
    float4_t v = ((const float4_t*)W2)[j];
    half4_t h; h[0]=(_Float16)v[0]; h[1]=(_Float16)v[1]; h[2]=(_Float16)v[2]; h[3]=(_Float16)v[3];
    ((half4_t*)(Wcat + 1048576))[j] = h;
  }
}

// ---------------------------------------------------------------------------
// K1: V = x@W1^T + b1 (=Q); K = x@W2^T + b2.  grid 512 = 64 bm x 8 bn.
// bn<4 -> V (+ fused V^T emission via LDS round-trip), bn>=4 -> K.
__global__ __launch_bounds__(512, 2) void gemm_vk_kernel(
    const _Float16* __restrict__ xh, const _Float16* __restrict__ Wcat,
    const float* __restrict__ b1, const float* __restrict__ b2,
    _Float16* __restrict__ Vbuf, _Float16* __restrict__ Kbuf,
    _Float16* __restrict__ Vt) {
  __shared__ _Float16 lds[65536];
  const int tid = threadIdx.x, lane = tid & 63, wave = tid >> 6;
  const int warp_m = wave >> 2, warp_n = wave & 3;
  const int m32 = lane & 31, ksel = lane >> 5;
  const int flat = blockIdx.x;
  const int wg = (flat & 7) * 64 + (flat >> 3);   // XCD-contiguous
  const int bm = wg >> 3, bn = wg & 7;
  const bool isV = bn < 4;
  const float* bias = isV ? b1 : b2;
  const int ncol0 = (bn & 3) * 256;
  float bv[2];
#pragma unroll
  for (int nt = 0; nt < 2; ++nt) bv[nt] = bias[ncol0 + COL32(nt) + m32];

  floatx16 acc[4][2] = {};
  gemm256_core((const char*)(xh + (size_t)bm * 256 * DIMK),
               (const char*)(Wcat + (size_t)bn * 256 * DIMK),
               DIMK * 2, DIMK * 2, DIMK / 64, lds, acc);

  _Float16* dst = isV ? Vbuf : Kbuf;
#pragma unroll
  for (int mt = 0; mt < 4; ++mt) {
#pragma unroll
    for (int nt = 0; nt < 2; ++nt) {
      const int col = ncol0 + COL32(nt) + m32;
#pragma unroll
      for (int reg = 0; reg < 16; ++reg) {
        const int row = bm * 256 + RL32(mt, reg);
        dst[(size_t)row * DIMK + col] = (_Float16)(acc[mt][nt][reg] + bv[nt]);
      }
    }
  }
  if (isV) {
    // Fused transpose: T[d][q] in LDS (256x256 halves, granule g ^= d&31),
    // then coalesced half8 stores of Vt[b][d][q].
    __syncthreads();
#pragma unroll
    for (int mt = 0; mt < 4; ++mt) {
#pragma unroll
      for (int nt = 0; nt < 2; ++nt) {
        const int d = COL32(nt) + m32;
        const float bb = bv[nt];
#pragma unroll
        for (int reg = 0; reg < 16; ++reg) {
          const int q = RL32(mt, reg);
          lds[d * 256 + ((((q >> 3) ^ d) & 31) << 3) + (q & 7)] = (_Float16)(acc[mt][nt][reg] + bb);
        }
      }
    }
    __syncthreads();
    const int b = bm >> 3, qb = (bm & 7) * 256;
    const size_t vtb = ((size_t)b * DIMK + ncol0) * SEQ + qb;
#pragma unroll
    for (int i = 0; i < 16; ++i) {
      const int idx = tid + i * 512;
      const int d = idx >> 5, G = idx & 31;
      half8 v = *(const half8*)(lds + d * 256 + (((G ^ d) & 31) << 3));
      *(half8*)(Vt + vtb + (size_t)d * SEQ + G * 8) = v;
    }
  }
}

// ---------------------------------------------------------------------------
// K2: P[b,k,q] = exp(scale * K.V^T) f16, plus per-block partial row-sums ->
// rsum_part[b][bn][row] (each slot written by exactly one block, no atomics).
// grid 512 = 8b x 8bm x 8bn (one batch per XCD).
__global__ __launch_bounds__(512, 2) void gemm_scores_kernel(
    const _Float16* __restrict__ Kb, const _Float16* __restrict__ Vb,
    _Float16* __restrict__ P, float* __restrict__ rsum_part) {
  __shared__ _Float16 lds[65536];
  const int tid = threadIdx.x, lane = tid & 63, wave = tid >> 6;
  const int warp_m = wave >> 2, warp_n = wave & 3;
  const int m32 = lane & 31, ksel = lane >> 5;
  const int flat = blockIdx.x;
  const int wg = (flat & 7) * 64 + (flat >> 3);
  const int b = wg >> 6, loc = wg & 63, bm = loc >> 3, bn = loc & 7;

  floatx16 acc[4][2] = {};
  gemm256_core((const char*)(Kb + (size_t)(b * SEQ + bm * 256) * DIMK),
               (const char*)(Vb + (size_t)(b * SEQ + bn * 256) * DIMK),
               DIMK * 2, DIMK * 2, DIMK / 64, lds, acc);

  __syncthreads();                 // core done; reuse LDS for partial sums
  float* part = (float*)lds;       // [4 warp_n][256 rows]
  _Float16* Pb = P + (size_t)b * SEQ * SEQ;
  const int colb = bn * 256 + warp_n * 32 + m32;
#pragma unroll
  for (int mt = 0; mt < 4; ++mt) {
#pragma unroll
    for (int reg = 0; reg < 16; ++reg) {
      const int rl = RL32(mt, reg);
      const _Float16 p0 = (_Float16)__expf(acc[mt][0][reg] * 0.03125f);
      const _Float16 p1 = (_Float16)__expf(acc[mt][1][reg] * 0.03125f);
      _Float16* prow = Pb + (size_t)(bm * 256 + rl) * SEQ + colb;
      prow[0]   = p0;
      prow[128] = p1;
      float s = (float)p0 + (float)p1;
      s += __shfl_xor(s, 1, 64);
      s += __shfl_xor(s, 2, 64);
      s += __shfl_xor(s, 4, 64);
      s += __shfl_xor(s, 8, 64);
      s += __shfl_xor(s, 16, 64);
      if (m32 == 0) part[warp_n * 256 + rl] = s;
    }
  }
  __syncthreads();
  if (tid < 256) {
    const float s = part[tid] + part[256 + tid] + part[512 + tid] + part[768 + tid];
    rsum_part[((size_t)b * 8 + bn) * SEQ + bm * 256 + tid] = s;
  }
}

// ---------------------------------------------------------------------------
// K3: out[b,k,d] = (sum_q P[b,k,q]*Vt[b,d,q]) / rowsum.  rowsum combined from
// the 8 per-bn partials in the epilogue (no in-loop VALU).  grid 256.
__global__ __launch_bounds__(512, 2) void gemm_out_kernel(
    const _Float16* __restrict__ P, const _Float16* __restrict__ Vt,
    const float* __restrict__ rsum_part, float* __restrict__ out) {
  __shared__ _Float16 lds[65536];
  const int tid = threadIdx.x, lane = tid & 63, wave = tid >> 6;
  const int warp_m = wave >> 2, warp_n = wave & 3;
  const int m32 = lane & 31, ksel = lane >> 5;
  const int flat = blockIdx.x;
  const int wg = (flat & 7) * 32 + (flat >> 3);
  const int b = wg >> 5, loc = wg & 31, bm = loc >> 2, bn = loc & 3;

  floatx16 acc[4][2] = {};
  gemm256_core((const char*)(P + (size_t)(b * SEQ + bm * 256) * SEQ),
               (const char*)(Vt + (size_t)(b * DIMK + bn * 256) * SEQ),
               SEQ * 2, SEQ * 2, SEQ / 64, lds, acc);

  __syncthreads();                 // core done; reuse LDS for inverse sums
  float* invf = (float*)lds;       // [256 rows]
  if (tid < 256) {
    const float* rp = rsum_part + (size_t)b * 8 * SEQ + bm * 256 + tid;
    float s = 0.f;
#pragma unroll
    for (int j = 0; j < 8; ++j) s += rp[j * SEQ];
    invf[tid] = __builtin_amdgcn_rcpf(s);  // ~1ulp, fine vs 2e-3 threshold
  }
  __syncthreads();

  float* ob = out + ((size_t)b * SEQ + bm * 256) * DIMK + bn * 256;
#pragma unroll
  for (int mt = 0; mt < 4; ++mt) {
#pragma unroll
    for (int reg = 0; reg < 16; ++reg) {
      const int row = RL32(mt, reg);
      const float inv = invf[row];
#pragma unroll
      for (int nt = 0; nt < 2; ++nt) {
        const int col = COL32(nt) + m32;
        ob[(size_t)row * DIMK + col] = acc[mt][nt][reg] * inv;
      }
    }
  }
}

// ---------------------------------------------------------------------------
extern "C" void kernel_launch(void* const* d_in, const int* in_sizes, int n_in,
                              void* d_out, int out_size, void* d_ws, size_t ws_size,
                              hipStream_t stream) {
  const float* x  = (const float*)d_in[0];
  const float* W1 = (const float*)d_in[1];
  const float* b1 = (const float*)d_in[2];
  const float* W2 = (const float*)d_in[3];
  const float* b2 = (const float*)d_in[4];
  float* out = (float*)d_out;

  // workspace layout (bytes), proven safe (172 MB total):
  //   region0 @ 0: xh f16 [16384x1024] (33.5 MB, dead after gemm_vk),
  //                then P f16 [8][2048][2048] (67 MB) overlaid
  //   Vt   f16 [8][1024][2048] @  67108864 (33,554,432)
  //   Vbuf f16 [16384x1024]    @ 100663296 (33,554,432)
  //   Kbuf f16 [16384x1024]    @ 134217728 (33,554,432)
  //   Wcat f16 [2048x1024]     @ 167772160 ( 4,194,304; dead after gemm_vk)
  //   rsum_part f32 [8][8][2048] @ 167772160 (524,288) -- overlays dead Wcat
  char* ws = (char*)d_ws;
  _Float16* xh   = (_Float16*)(ws);
  _Float16* Pbuf = (_Float16*)(ws);
  _Float16* Vt   = (_Float16*)(ws + 67108864);
  _Float16* Vbuf = (_Float16*)(ws + 100663296);
  _Float16* Kbuf = (_Float16*)(ws + 134217728);
  _Float16* Wcat = (_Float16*)(ws + 167772160);
  float* rsum_part = (float*)(ws + 167772160);   // overlays Wcat (dead by then)

  prep_kernel<<<18432, 256, 0, stream>>>(x, W1, W2, xh, Wcat);
  gemm_vk_kernel<<<512, 512, 0, stream>>>(xh, Wcat, b1, b2, Vbuf, Kbuf, Vt);
  gemm_scores_kernel<<<512, 512, 0, stream>>>(Kbuf, Vbuf, Pbuf, rsum_part);
  gemm_out_kernel<<<256, 512, 0, stream>>>(Pbuf, Vt, rsum_part, out);
}

// Round 4
// 327.115 us; speedup vs baseline: 1.1300x; 1.1300x over previous
//
#include <hip/hip_runtime.h>
#include <hip/hip_fp16.h>
#include <cstdint>
#include <cstddef>

// Problem constants
#define DIMK 1024
#define NBATCH 8
#define SEQ 2048

typedef _Float16 half8 __attribute__((ext_vector_type(8)));
typedef _Float16 half4_t __attribute__((ext_vector_type(4)));
typedef float float4_t __attribute__((ext_vector_type(4)));

// async global->LDS 16B copy (gfx950). LDS dest is wave-uniform base + lane*16.
__device__ __forceinline__ void gload16(const _Float16* g, _Float16* l) {
  __builtin_amdgcn_global_load_lds((const __attribute__((address_space(1))) void*)g,
                                   (__attribute__((address_space(3))) void*)l, 16, 0, 0);
}

#define BAR() asm volatile("s_barrier" ::: "memory")
#define LGKM(n) asm volatile("s_waitcnt lgkmcnt(" #n ")" ::: "memory")
#define VMW(n) asm volatile("s_waitcnt vmcnt(" #n ")" ::: "memory")
#define PRIO1() __builtin_amdgcn_s_setprio(1)
#define PRIO0() __builtin_amdgcn_s_setprio(0)
#define SCHED0() __builtin_amdgcn_sched_barrier(0)

// ---------------------------------------------------------------------------
// 256x256-tile NT f16 GEMM core, BK=64, 512 threads = 8 waves (2M x 4N),
// v_mfma_f32_16x16x32_f16 (proven 0-bank-conflict read geometry).
// SOFTWARE-PIPELINED 4-phase schedule: fragments for each MFMA quad are
// ds_read ONE PHASE EARLY, so the LDS pipe services reads while the matrix
// pipe runs the current quad (they were serialized before: ~4800 cyc/tile ->
// target ~max(2483 MFMA, ~2300 LDS) + barrier overhead).
//   Ph1: VMW(6); read F2=B-hi(t);  lgkm(4)  [F1 done]; Q(0,0)=A-lo*B-lo; STG(t+1,A-bot); BAR
//   Ph2:         read F3=A-hi(t);  lgkm(8)  [F2 done]; Q(0,1)=A-lo*B-hi; STG(t+2,A-top); BAR
//   Ph3: VMW(6);                   lgkm(0)  [F3 done]; Q(1,1)=A-hi*B-hi; STG(t+2,B-top); BAR
//   Ph4:         Q(1,0)=A-hi*B-lo; read F1=A-lo+B-lo(t+1); VMW(6); STG(t+2,B-bot); BAR
// vmcnt(6) = 3 newest STG pairs allowed outstanding; each VMW forces exactly
// the staging pairs needed by reads that follow the NEXT barrier (cross-wave
// safety: a wave's loads are complete before it passes the barrier preceding
// any other wave's reads of that region). lgkm counts are per-wave FIFO.
// LDS 128 KiB: [A|B] x 2 parities; 16B-granule XOR swizzle g^(row&7), staging
// pre-swizzles the per-lane GLOBAL source so the LDS dest stays linear.
// A/B frag (16x16x32): m/n = lane&15, k = (lane>>4)*8+j.
// C/D: col = lane&15, row = (lane>>4)*4 + reg.
// ---------------------------------------------------------------------------
__device__ __forceinline__ void gemm256_core(
    const char* __restrict__ Ab, const char* __restrict__ Bb,
    const int ldA, const int ldB, const int NT, _Float16* lds,
    float4_t (&acc)[8][4])
{
  const int tid = threadIdx.x;
  const int lane = tid & 63, wave = tid >> 6;
  const int warp_m = wave >> 2, warp_n = wave & 3;
  const int srow = lane >> 3;                    // staging sub-row in 8-row chunk
  const int scb = ((lane & 7) ^ srow) << 4;      // pre-swizzled source col-byte
  const int c0 = wave * 2;                       // this wave's 1KB chunk pair
  const int fr = lane & 15, fg = lane >> 4, rsw = lane & 7;

  // loop-invariant LDS read offsets (halves)
  const int xo0 = (fg ^ rsw) << 3;
  const int xo1 = ((4 + fg) ^ rsw) << 3;
  const int aro = (warp_m * 64 + fr) * 64;           // A row base
  const int bro = 16384 + (warp_n * 32 + fr) * 64;   // B row base (B region)

  // loop-invariant staging bases
  _Float16* const sA = lds + c0 * 512;
  _Float16* const sB = lds + 16384 + c0 * 512;
  const char* const gA = Ab + (size_t)(c0 * 8 + srow) * ldA + scb;
  const char* const gB = Bb + (size_t)(c0 * 8 + srow) * ldB + scb;
  const size_t ldA8 = (size_t)ldA * 8,   ldB8 = (size_t)ldB * 8;
  const size_t ldA128 = (size_t)ldA * 128, ldB128 = (size_t)ldB * 128;

  half8 AfLo[4][2], AfHi[4][2], Bf0[2][2], Bf1[2][2];

#define STG_A(pbuf, ob_, bot) do { \
    _Float16* _lb = sA + (pbuf) + ((bot) ? 8192 : 0); \
    const char* _g = gA + ((bot) ? ldA128 : 0) + (size_t)(ob_); \
    gload16((const _Float16*)_g, _lb); \
    gload16((const _Float16*)(_g + ldA8), _lb + 512); } while (0)
#define STG_B(pbuf, ob_, bot) do { \
    _Float16* _lb = sB + (pbuf) + ((bot) ? 8192 : 0); \
    const char* _g = gB + ((bot) ? ldB128 : 0) + (size_t)(ob_); \
    gload16((const _Float16*)_g, _lb); \
    gload16((const _Float16*)(_g + ldB8), _lb + 512); } while (0)

// A fragments, row-half g (g=0: rows [0,128); g=1: +128): 8 x ds_read_b128
#define RDA(DST, pbase, g) do { \
    _Pragma("unroll") for (int m = 0; m < 4; ++m) { \
      DST[m][0] = *(const half8*)(lds + (pbase) + aro + (g) * 8192 + m * 1024 + xo0); \
      DST[m][1] = *(const half8*)(lds + (pbase) + aro + (g) * 8192 + m * 1024 + xo1); \
    } } while (0)
// B fragments, col-half g: 4 x ds_read_b128
#define RDB(DST, pbase, g) do { \
    _Pragma("unroll") for (int n = 0; n < 2; ++n) { \
      DST[n][0] = *(const half8*)(lds + (pbase) + bro + (g) * 8192 + n * 1024 + xo0); \
      DST[n][1] = *(const half8*)(lds + (pbase) + bro + (g) * 8192 + n * 1024 + xo1); \
    } } while (0)

#define QUAD(gm, gn, AF, BF) do { \
    _Pragma("unroll") for (int m = 0; m < 4; ++m) \
    _Pragma("unroll") for (int n = 0; n < 2; ++n) \
    _Pragma("unroll") for (int kk = 0; kk < 2; ++kk) \
      acc[(gm) * 4 + m][(gn) * 2 + n] = __builtin_amdgcn_mfma_f32_16x16x32_f16( \
          AF[m][kk], BF[n][kk], acc[(gm) * 4 + m][(gn) * 2 + n], 0, 0, 0); \
  } while (0)

  // prologue: tile0 (A-top,B-top,B-bot,A-bot) + tile1 (A-top,B-top,B-bot)
  STG_A(0, 0, 0); STG_B(0, 0, 0); STG_B(0, 0, 1); STG_A(0, 0, 1);
  STG_A(32768, 128, 0); STG_B(32768, 128, 0); STG_B(32768, 128, 1);
  VMW(8);                    // pairs 1-3 (A-top0,B-top0,B-bot0) done
  BAR();
  RDA(AfLo, 0, 0);           // F1(0): A-lo
  RDB(Bf0, 0, 0);            //        B-lo

  int t = 0;
  for (; t + 2 < NT; ++t) {
    const int pb = (t & 1) << 15, pbn = pb ^ 32768;
    const int o1 = (t + 1) << 7, o2 = (t + 2) << 7;
    // Ph1
    VMW(6);                               // forces S(t,A-bot)+older done
    RDB(Bf1, pb, 1);                      // F2(t): B-hi
    LGKM(4); SCHED0();
    PRIO1(); QUAD(0, 0, AfLo, Bf0); PRIO0();
    STG_A(pbn, o1, 1);                    // S(t+1, A-bot)
    BAR();
    // Ph2
    RDA(AfHi, pb, 1);                     // F3(t): A-hi
    LGKM(8); SCHED0();
    PRIO1(); QUAD(0, 1, AfLo, Bf1); PRIO0();
    STG_A(pb, o2, 0);                     // S(t+2, A-top)
    BAR();
    // Ph3
    VMW(6);                               // forces S(t+1,B-top)+older done
    LGKM(0); SCHED0();
    PRIO1(); QUAD(1, 1, AfHi, Bf1); PRIO0();
    STG_B(pb, o2, 0);                     // S(t+2, B-top)
    BAR();
    // Ph4: MFMA first (consumes Bf0/AfHi), then prefetch next tile's F1
    PRIO1(); QUAD(1, 0, AfHi, Bf0); PRIO0();
    RDA(AfLo, pbn, 0);                    // F1(t+1): A-lo (next parity)
    RDB(Bf0, pbn, 0);                     //          B-lo
    VMW(6);                               // forces S(t+1,B-bot)+older done
    STG_B(pb, o2, 1);                     // S(t+2, B-bot)
    BAR();
  }
  // tile NT-2: stage only S(NT-1,A-bot), then full drain
  {
    const int pb = (t & 1) << 15, pbn = pb ^ 32768;
    const int oL = (NT - 1) << 7;
    VMW(6);
    RDB(Bf1, pb, 1);
    LGKM(4); SCHED0();
    PRIO1(); QUAD(0, 0, AfLo, Bf0); PRIO0();
    STG_A(pbn, oL, 1);                    // S(NT-1, A-bot)
    BAR();
    RDA(AfHi, pb, 1);
    LGKM(8); SCHED0();
    PRIO1(); QUAD(0, 1, AfLo, Bf1); PRIO0();
    BAR();
    LGKM(0); SCHED0();
    PRIO1(); QUAD(1, 1, AfHi, Bf1); PRIO0();
    PRIO1(); QUAD(1, 0, AfHi, Bf0); PRIO0();
    VMW(0);                               // all staging (incl. A-bot) done
    BAR();
  }
  // tile NT-1: fully resident, serial (compiler-managed waits)
  {
    const int pb = ((NT - 1) & 1) << 15;
    RDA(AfLo, pb, 0); RDB(Bf0, pb, 0); RDB(Bf1, pb, 1);
    QUAD(0, 0, AfLo, Bf0); QUAD(0, 1, AfLo, Bf1);
    RDA(AfHi, pb, 1);
    QUAD(1, 1, AfHi, Bf1); QUAD(1, 0, AfHi, Bf0);
  }
#undef STG_A
#undef STG_B
#undef RDA
#undef RDB
#undef QUAD
}

// C-tile coordinate helpers (interleaved wave sub-tiles)
#define ROW_LOCAL(mi) (warp_m * 64 + ((mi) & 3) * 16 + (((mi) >> 2) ? 128 : 0))
#define COL_LOCAL(nj) (warp_n * 32 + (((nj) & 1) ? 16 : 0) + (((nj) >> 1) ? 128 : 0))

// ---------------------------------------------------------------------------
// One-shot prep: cvt x (4194304 quads), W1 (262144), W2 (262144) to f16.
__global__ __launch_bounds__(256) void prep_kernel(const float* __restrict__ x,
                                                   const float* __restrict__ W1,
                                                   const float* __restrict__ W2,
                                                   _Float16* __restrict__ xh,
                                                   _Float16* __restrict__ Wcat) {
  int i = blockIdx.x * 256 + threadIdx.x;
  if (i < 4194304) {
    float4_t v = ((const float4_t*)x)[i];
    half4_t h; h[0]=(_Float16)v[0]; h[1]=(_Float16)v[1]; h[2]=(_Float16)v[2]; h[3]=(_Float16)v[3];
    ((half4_t*)xh)[i] = h;
  } else if (i < 4456448) {
    int j = i - 4194304;
    float4_t v = ((const float4_t*)W1)[j];
    half4_t h; h[0]=(_Float16)v[0]; h[1]=(_Float16)v[1]; h[2]=(_Float16)v[2]; h[3]=(_Float16)v[3];
    ((half4_t*)Wcat)[j] = h;
  } else if (i < 4718592) {
    int j = i - 4456448;
    float4_t v = ((const float4_t*)W2)[j];
    half4_t h; h[0]=(_Float16)v[0]; h[1]=(_Float16)v[1]; h[2]=(_Float16)v[2]; h[3]=(_Float16)v[3];
    ((half4_t*)(Wcat + 1048576))[j] = h;
  }
}

// ---------------------------------------------------------------------------
// K1: V = x@W1^T + b1 (=Q); K = x@W2^T + b2.  grid 512 = 64 bm x 8 bn.
// bn<4 -> V (+ fused V^T emission via LDS round-trip), bn>=4 -> K.
__global__ __launch_bounds__(512, 2) void gemm_vk_kernel(
    const _Float16* __restrict__ xh, const _Float16* __restrict__ Wcat,
    const float* __restrict__ b1, const float* __restrict__ b2,
    _Float16* __restrict__ Vbuf, _Float16* __restrict__ Kbuf,
    _Float16* __restrict__ Vt) {
  __shared__ _Float16 lds[65536];
  const int tid = threadIdx.x, lane = tid & 63, wave = tid >> 6;
  const int warp_m = wave >> 2, warp_n = wave & 3;
  const int fr = lane & 15, rb = (lane >> 4) * 4;
  const int flat = blockIdx.x;
  const int wg = (flat & 7) * 64 + (flat >> 3);   // XCD-contiguous
  const int bm = wg >> 3, bn = wg & 7;
  const bool isV = bn < 4;
  const float* bias = isV ? b1 : b2;
  const int ncol0 = (bn & 3) * 256;
  float bv[4];
#pragma unroll
  for (int nj = 0; nj < 4; ++nj) bv[nj] = bias[ncol0 + COL_LOCAL(nj) + fr];

  float4_t acc[8][4] = {};
  gemm256_core((const char*)(xh + (size_t)bm * 256 * DIMK),
               (const char*)(Wcat + (size_t)bn * 256 * DIMK),
               DIMK * 2, DIMK * 2, DIMK / 64, lds, acc);

  _Float16* dst = isV ? Vbuf : Kbuf;
#pragma unroll
  for (int mi = 0; mi < 8; ++mi) {
    const int row = bm * 256 + ROW_LOCAL(mi) + rb;
#pragma unroll
    for (int nj = 0; nj < 4; ++nj) {
      const int col = ncol0 + COL_LOCAL(nj) + fr;
#pragma unroll
      for (int r = 0; r < 4; ++r)
        dst[(size_t)(row + r) * DIMK + col] = (_Float16)(acc[mi][nj][r] + bv[nj]);
    }
  }
  if (isV) {
    // Fused transpose: T[d][q] in LDS (256x256 halves, granule g ^= d&31),
    // then coalesced half8 stores of Vt[b][d][q].
    __syncthreads();
#pragma unroll
    for (int mi = 0; mi < 8; ++mi) {
      const int q0 = ROW_LOCAL(mi) + rb;
#pragma unroll
      for (int nj = 0; nj < 4; ++nj) {
        const int d = COL_LOCAL(nj) + fr;
        const float bb = bv[nj];
#pragma unroll
        for (int r = 0; r < 4; ++r) {
          const int q = q0 + r;
          lds[d * 256 + ((((q >> 3) ^ d) & 31) << 3) + (q & 7)] = (_Float16)(acc[mi][nj][r] + bb);
        }
      }
    }
    __syncthreads();
    const int b = bm >> 3, qb = (bm & 7) * 256;
    const size_t vtb = ((size_t)b * DIMK + ncol0) * SEQ + qb;
#pragma unroll
    for (int i = 0; i < 16; ++i) {
      const int idx = tid + i * 512;
      const int d = idx >> 5, G = idx & 31;
      half8 v = *(const half8*)(lds + d * 256 + (((G ^ d) & 31) << 3));
      *(half8*)(Vt + vtb + (size_t)d * SEQ + G * 8) = v;
    }
  }
}

// ---------------------------------------------------------------------------
// K2: P[b,k,q] = exp(scale * K.V^T) f16, plus per-block partial row-sums ->
// rsum_part[b][bn][row] (each slot written by exactly one block, no atomics).
// grid 512 = 8b x 8bm x 8bn (one batch per XCD).
__global__ __launch_bounds__(512, 2) void gemm_scores_kernel(
    const _Float16* __restrict__ Kb, const _Float16* __restrict__ Vb,
    _Float16* __restrict__ P, float* __restrict__ rsum_part) {
  __shared__ _Float16 lds[65536];
  const int tid = threadIdx.x, lane = tid & 63, wave = tid >> 6;
  const int warp_m = wave >> 2, warp_n = wave & 3;
  const int fr = lane & 15, rb = (lane >> 4) * 4;
  const int flat = blockIdx.x;
  const int wg = (flat & 7) * 64 + (flat >> 3);
  const int b = wg >> 6, loc = wg & 63, bm = loc >> 3, bn = loc & 7;

  float4_t acc[8][4] = {};
  gemm256_core((const char*)(Kb + (size_t)(b * SEQ + bm * 256) * DIMK),
               (const char*)(Vb + (size_t)(b * SEQ + bn * 256) * DIMK),
               DIMK * 2, DIMK * 2, DIMK / 64, lds, acc);

  __syncthreads();                 // core done; reuse LDS for partial sums
  float* part = (float*)lds;       // [4 warp_n][256 rows]
  _Float16* Pb = P + (size_t)b * SEQ * SEQ;
#pragma unroll
  for (int mi = 0; mi < 8; ++mi) {
    const int rl = ROW_LOCAL(mi) + rb;
#pragma unroll
    for (int r = 0; r < 4; ++r) {
      float s = 0.f;
#pragma unroll
      for (int nj = 0; nj < 4; ++nj) {
        const int col = bn * 256 + COL_LOCAL(nj) + fr;
        const _Float16 ph = (_Float16)__expf(acc[mi][nj][r] * 0.03125f);
        Pb[(size_t)(bm * 256 + rl + r) * SEQ + col] = ph;
        s += (float)ph;
      }
      s += __shfl_xor(s, 1, 64);
      s += __shfl_xor(s, 2, 64);
      s += __shfl_xor(s, 4, 64);
      s += __shfl_xor(s, 8, 64);
      if (fr == 0) part[warp_n * 256 + rl + r] = s;
    }
  }
  __syncthreads();
  if (tid < 256) {
    const float s = part[tid] + part[256 + tid] + part[512 + tid] + part[768 + tid];
    rsum_part[((size_t)b * 8 + bn) * SEQ + bm * 256 + tid] = s;
  }
}

// ---------------------------------------------------------------------------
// K3: out[b,k,d] = (sum_q P[b,k,q]*Vt[b,d,q]) / rowsum.  rowsum combined from
// the 8 per-bn partials in the epilogue (no in-loop VALU).  grid 256.
__global__ __launch_bounds__(512, 2) void gemm_out_kernel(
    const _Float16* __restrict__ P, const _Float16* __restrict__ Vt,
    const float* __restrict__ rsum_part, float* __restrict__ out) {
  __shared__ _Float16 lds[65536];
  const int tid = threadIdx.x, lane = tid & 63, wave = tid >> 6;
  const int warp_m = wave >> 2, warp_n = wave & 3;
  const int fr = lane & 15, rb = (lane >> 4) * 4;
  const int flat = blockIdx.x;
  const int wg = (flat & 7) * 32 + (flat >> 3);
  const int b = wg >> 5, loc = wg & 31, bm = loc >> 2, bn = loc & 3;

  float4_t acc[8][4] = {};
  gemm256_core((const char*)(P + (size_t)(b * SEQ + bm * 256) * SEQ),
               (const char*)(Vt + (size_t)(b * DIMK + bn * 256) * SEQ),
               SEQ * 2, SEQ * 2, SEQ / 64, lds, acc);

  __syncthreads();                 // core done; reuse LDS for inverse sums
  float* invf = (float*)lds;       // [256 rows]
  if (tid < 256) {
    const float* rp = rsum_part + (size_t)b * 8 * SEQ + bm * 256 + tid;
    float s = 0.f;
#pragma unroll
    for (int j = 0; j < 8; ++j) s += rp[j * SEQ];
    invf[tid] = __builtin_amdgcn_rcpf(s);  // ~1ulp, fine vs 2e-3 threshold
  }
  __syncthreads();

  float* ob = out + ((size_t)b * SEQ + bm * 256) * DIMK + bn * 256;
#pragma unroll
  for (int mi = 0; mi < 8; ++mi) {
#pragma unroll
    for (int r = 0; r < 4; ++r) {
      const int row = ROW_LOCAL(mi) + rb + r;
      const float inv = invf[row];
#pragma unroll
      for (int nj = 0; nj < 4; ++nj) {
        const int col = COL_LOCAL(nj) + fr;
        ob[(size_t)row * DIMK + col] = acc[mi][nj][r] * inv;
      }
    }
  }
}

// ---------------------------------------------------------------------------
extern "C" void kernel_launch(void* const* d_in, const int* in_sizes, int n_in,
                              void* d_out, int out_size, void* d_ws, size_t ws_size,
                              hipStream_t stream) {
  const float* x  = (const float*)d_in[0];
  const float* W1 = (const float*)d_in[1];
  const float* b1 = (const float*)d_in[2];
  const float* W2 = (const float*)d_in[3];
  const float* b2 = (const float*)d_in[4];
  float* out = (float*)d_out;

  // workspace layout (bytes), proven safe (172 MB total):
  //   region0 @ 0: xh f16 [16384x1024] (33.5 MB, dead after gemm_vk),
  //                then P f16 [8][2048][2048] (67 MB) overlaid
  //   Vt   f16 [8][1024][2048] @  67108864 (33,554,432)
  //   Vbuf f16 [16384x1024]    @ 100663296 (33,554,432)
  //   Kbuf f16 [16384x1024]    @ 134217728 (33,554,432)
  //   Wcat f16 [2048x1024]     @ 167772160 ( 4,194,304; dead after gemm_vk)
  //   rsum_part f32 [8][8][2048] @ 167772160 (524,288) -- overlays dead Wcat
  char* ws = (char*)d_ws;
  _Float16* xh   = (_Float16*)(ws);
  _Float16* Pbuf = (_Float16*)(ws);
  _Float16* Vt   = (_Float16*)(ws + 67108864);
  _Float16* Vbuf = (_Float16*)(ws + 100663296);
  _Float16* Kbuf = (_Float16*)(ws + 134217728);
  _Float16* Wcat = (_Float16*)(ws + 167772160);
  float* rsum_part = (float*)(ws + 167772160);   // overlays Wcat (dead by then)

  prep_kernel<<<18432, 256, 0, stream>>>(x, W1, W2, xh, Wcat);
  gemm_vk_kernel<<<512, 512, 0, stream>>>(xh, Wcat, b1, b2, Vbuf, Kbuf, Vt);
  gemm_scores_kernel<<<512, 512, 0, stream>>>(Kbuf, Vbuf, Pbuf, rsum_part);
  gemm_out_kernel<<<256, 512, 0, stream>>>(Pbuf, Vt, rsum_part, out);
}